// Round 5
// baseline (177.050 us; speedup 1.0000x reference)
//
#include <hip/hip_runtime.h>
#include <math.h>

// DetectionLayer, fully wave-synchronous: each 64-lane wave owns 16 cells
// end-to-end (private LDS slice, private input/output ranges). ZERO block
// barriers -> waves drift freely, store traffic flows continuously.
//   A : wave loads its 16 rows (1680 floats = 420 float4) -> LDS
//   B1: lane (c=lane&15, part=lane>>4) sums 20 exps; 2 shfl_xor -> inv_sum
//   B2: (cell,anchor) pairs: sigmoids, boxes, conf, scale = conf*inv
//   C : (cell,class4) chunks: 4 exps, 5 scaled float4 stores (dense lines)
// d_out (f32): b_pred_loc [N,5,4] | b_cls [N,5,80] | b_conf [N,5], N=B*784.

#define CPW 16      // cells per wave
#define ROW 105     // floats per cell

__device__ __forceinline__ float fsig(float x) {
    return __builtin_amdgcn_rcpf(1.0f + __expf(-x));
}

__global__ __launch_bounds__(256) void det_fused(
    const float* __restrict__ in, float* __restrict__ out,
    int total_cells, size_t cls_off, size_t conf_off)
{
    __shared__ float s_row[4][CPW * ROW];   // 26880 B
    __shared__ float s_scale[4][CPW * 5];   // conf * inv_sum

    const int w    = threadIdx.x >> 6;
    const int lane = threadIdx.x & 63;
    const int cell0 = (blockIdx.x * 4 + w) * CPW;   // this wave's first cell
    if (cell0 >= total_cells) return;
    const int ncell = min(CPW, total_cells - cell0);

    float* __restrict__ row = s_row[w];
    float* __restrict__ scl = s_scale[w];

    // ---- A: wave-private coalesced load into LDS ----
    {
        const float* __restrict__ src = in + (size_t)cell0 * ROW;
        const int nflt = ncell * ROW;
        const int nv = nflt >> 2;
        const float4* __restrict__ s4 = reinterpret_cast<const float4*>(src);
        float4* d4 = reinterpret_cast<float4*>(row);
        for (int i = lane; i < nv; i += 64) d4[i] = s4[i];
        for (int i = (nv << 2) + lane; i < nflt; i += 64) row[i] = src[i];
    }
    __builtin_amdgcn_wave_barrier();

    // ---- B1: softmax inv-denominator, kept in registers via 2 shuffles ----
    float inv_c;                                   // valid for c = lane&15
    {
        const int c = lane & 15;                   // cell within wave
        const int part = lane >> 4;                // 0..3, 20 logits each
        float s = 0.0f;
        const float* __restrict__ r = row + c * ROW + 25 + part * 20;
        #pragma unroll
        for (int j = 0; j < 20; ++j) s += __expf(r[j]);
        s += __shfl_xor(s, 16);
        s += __shfl_xor(s, 32);
        inv_c = __builtin_amdgcn_rcpf(s);          // every lane: sum for its c
    }
    __builtin_amdgcn_wave_barrier();

    // ---- B2: sigmoids, boxes, conf, scales ----
    // scale needs inv for cell p/5; lane holds inv for cell lane&15, so fetch
    // via one shuffle per pair: src lane = (p/5) (lanes 0..15 hold cells 0..15).
    for (int p = lane; p < ncell * 5; p += 64) {
        const int c = p / 5;
        const int a = p - c * 5;
        const float inv = __shfl(inv_c, c);        // c < 16
        const float* __restrict__ lc = row + c * ROW + a * 5;
        const float sx = fsig(lc[0]);
        const float sy = fsig(lc[1]);
        const float sw = fsig(lc[2]);
        const float sh = fsig(lc[3]);
        const float cf = fsig(lc[4]);
        scl[p] = cf * inv;

        const int gcell = cell0 + c;
        out[conf_off + (size_t)gcell * 5 + a] = cf;

        const int cell28 = gcell % 784;            // gy*28 + gx
        const float gx = (float)(cell28 % 28);
        const float gy = (float)(cell28 / 28);
        const float invS = 1.0f / 28.0f;
        const float px = (sx + gx) * invS;
        const float py = (sy + gy) * invS;
        const float hw = sw * 0.5f;
        const float hh = sh * 0.5f;
        float4 box = make_float4(px - hw, py - hh, px + hw, py + hh);
        *reinterpret_cast<float4*>(out + ((size_t)gcell * 5 + a) * 4) = box;
    }
    __builtin_amdgcn_wave_barrier();

    // ---- C: b_cls, exp once per chunk, 5 anchor-scaled float4 stores ----
    {
        float* __restrict__ cls = out + cls_off + (size_t)cell0 * 400;
        const int nchunk = ncell * 20;
        for (int i = lane; i < nchunk; i += 64) {
            const int c = i / 20;
            const int c4 = i - c * 20;
            const float* __restrict__ lp = row + c * ROW + 25 + c4 * 4;
            const float e0 = __expf(lp[0]);
            const float e1 = __expf(lp[1]);
            const float e2 = __expf(lp[2]);
            const float e3 = __expf(lp[3]);
            const float* __restrict__ sc = scl + c * 5;
            float* __restrict__ cp = cls + (size_t)c * 400 + c4 * 4;
            #pragma unroll
            for (int a = 0; a < 5; ++a) {
                const float s = sc[a];
                float4 o = make_float4(e0 * s, e1 * s, e2 * s, e3 * s);
                *reinterpret_cast<float4*>(cp + a * 80) = o;
            }
        }
    }
}

extern "C" void kernel_launch(void* const* d_in, const int* in_sizes, int n_in,
                              void* d_out, int out_size, void* d_ws, size_t ws_size,
                              hipStream_t stream) {
    const float* in = (const float*)d_in[0];
    float* out = (float*)d_out;

    const size_t total_cells = (size_t)in_sizes[0] / 105;   // B * 784
    const size_t anchors     = total_cells * 5;
    const size_t cls_off     = anchors * 4;                 // after b_pred_loc
    const size_t conf_off    = cls_off + anchors * 80;      // after b_cls

    const int cells_per_block = 4 * CPW;                    // 64
    const int blocks = (int)((total_cells + cells_per_block - 1) / cells_per_block);
    det_fused<<<blocks, 256, 0, stream>>>(in, out, (int)total_cells,
                                          cls_off, conf_off);
}

// Round 6
// 164.680 us; speedup vs baseline: 1.0751x; 1.0751x over previous
//
#include <hip/hip_runtime.h>
#include <math.h>

// DetectionLayer, wave-synchronous, LINEAR-store phase C:
//   each 64-lane wave owns 16 cells end-to-end (private LDS slice).
//   A : wave loads its 16 rows (1680 floats) -> LDS, coalesced float4
//   B1: lane (c=lane&15, part=lane>>4) sums 20 exps; 2 shfl_xor -> inv_sum
//   B2: (cell,anchor) pairs: sigmoids, boxes, conf, scale = conf*inv -> LDS
//   C : lane <-> linear float4 of b_cls: every store instruction is a fully
//       contiguous, 128B-aligned 1KB burst (fill-kernel store shape).
//       exp recomputed per anchor (trans pipe has 15x headroom).
// d_out (f32): b_pred_loc [N,5,4] | b_cls [N,5,80] | b_conf [N,5], N=B*784.

#define CPW 16      // cells per wave
#define ROW 105     // floats per cell

__device__ __forceinline__ float fsig(float x) {
    return __builtin_amdgcn_rcpf(1.0f + __expf(-x));
}

__global__ __launch_bounds__(256) void det_fused(
    const float* __restrict__ in, float* __restrict__ out,
    int total_cells, size_t cls_off, size_t conf_off)
{
    __shared__ float s_row[4][CPW * ROW];   // 26880 B
    __shared__ float s_scale[4][CPW * 5];   // conf * inv_sum

    const int w    = threadIdx.x >> 6;
    const int lane = threadIdx.x & 63;
    const int cell0 = (blockIdx.x * 4 + w) * CPW;   // this wave's first cell
    if (cell0 >= total_cells) return;
    const int ncell = min(CPW, total_cells - cell0);

    float* __restrict__ row = s_row[w];
    float* __restrict__ scl = s_scale[w];

    // ---- A: wave-private coalesced load into LDS ----
    {
        const float* __restrict__ src = in + (size_t)cell0 * ROW;
        const int nflt = ncell * ROW;
        const int nv = nflt >> 2;
        const float4* __restrict__ s4 = reinterpret_cast<const float4*>(src);
        float4* d4 = reinterpret_cast<float4*>(row);
        for (int i = lane; i < nv; i += 64) d4[i] = s4[i];
        for (int i = (nv << 2) + lane; i < nflt; i += 64) row[i] = src[i];
    }
    __builtin_amdgcn_wave_barrier();

    // ---- B1: softmax inv-denominator, kept in registers via 2 shuffles ----
    float inv_c;                                   // valid for c = lane&15
    {
        const int c = lane & 15;                   // cell within wave
        const int part = lane >> 4;                // 0..3, 20 logits each
        float s = 0.0f;
        const float* __restrict__ r = row + c * ROW + 25 + part * 20;
        #pragma unroll
        for (int j = 0; j < 20; ++j) s += __expf(r[j]);
        s += __shfl_xor(s, 16);
        s += __shfl_xor(s, 32);
        inv_c = __builtin_amdgcn_rcpf(s);          // every lane: sum for its c
    }
    __builtin_amdgcn_wave_barrier();

    // ---- B2: sigmoids, boxes, conf, scales ----
    for (int p = lane; p < ncell * 5; p += 64) {
        const int c = p / 5;
        const int a = p - c * 5;
        const float inv = __shfl(inv_c, c);        // c < 16
        const float* __restrict__ lc = row + c * ROW + a * 5;
        const float sx = fsig(lc[0]);
        const float sy = fsig(lc[1]);
        const float sw = fsig(lc[2]);
        const float sh = fsig(lc[3]);
        const float cf = fsig(lc[4]);
        scl[p] = cf * inv;

        const int gcell = cell0 + c;
        out[conf_off + (size_t)gcell * 5 + a] = cf;

        const int cell28 = gcell % 784;            // gy*28 + gx
        const float gx = (float)(cell28 % 28);
        const float gy = (float)(cell28 / 28);
        const float invS = 1.0f / 28.0f;
        const float px = (sx + gx) * invS;
        const float py = (sy + gy) * invS;
        const float hw = sw * 0.5f;
        const float hh = sh * 0.5f;
        float4 box = make_float4(px - hw, py - hh, px + hw, py + hh);
        *reinterpret_cast<float4*>(out + ((size_t)gcell * 5 + a) * 4) = box;
    }
    __builtin_amdgcn_wave_barrier();

    // ---- C: b_cls, lane <-> linear float4 => contiguous 1KB store bursts ----
    {
        float4* __restrict__ cls4 =
            reinterpret_cast<float4*>(out + cls_off + (size_t)cell0 * 400);
        const int nvec = ncell * 100;              // float4 count for this wave
        for (int v = lane; v < nvec; v += 64) {
            const int c  = v / 100;                // cell in wave
            const int r  = v - c * 100;
            const int a  = r / 20;                 // anchor
            const int c4 = r - a * 20;             // class group
            const float* __restrict__ lp = row + c * ROW + 25 + c4 * 4;
            const float s = scl[c * 5 + a];
            float4 o;
            o.x = __expf(lp[0]) * s;
            o.y = __expf(lp[1]) * s;
            o.z = __expf(lp[2]) * s;
            o.w = __expf(lp[3]) * s;
            cls4[v] = o;
        }
    }
}

extern "C" void kernel_launch(void* const* d_in, const int* in_sizes, int n_in,
                              void* d_out, int out_size, void* d_ws, size_t ws_size,
                              hipStream_t stream) {
    const float* in = (const float*)d_in[0];
    float* out = (float*)d_out;

    const size_t total_cells = (size_t)in_sizes[0] / 105;   // B * 784
    const size_t anchors     = total_cells * 5;
    const size_t cls_off     = anchors * 4;                 // after b_pred_loc
    const size_t conf_off    = cls_off + anchors * 80;      // after b_cls

    const int cells_per_block = 4 * CPW;                    // 64
    const int blocks = (int)((total_cells + cells_per_block - 1) / cells_per_block);
    det_fused<<<blocks, 256, 0, stream>>>(in, out, (int)total_cells,
                                          cls_off, conf_off);
}

// Round 8
// 136.133 us; speedup vs baseline: 1.3006x; 1.2097x over previous
//
#include <hip/hip_runtime.h>
#include <math.h>

// DetectionLayer, wave-synchronous, linear-store phase C + NONTEMPORAL stores:
//   each 64-lane wave owns 16 cells end-to-end (private LDS slice).
//   A : wave loads its 16 rows (1680 floats) -> LDS, coalesced float4
//   B1: lane (c=lane&15, part=lane>>4) sums 20 exps; 2 shfl_xor -> inv_sum
//   B2: (cell,anchor) pairs: sigmoids, boxes, conf, scale = conf*inv -> LDS
//   C : lane <-> linear float4 of b_cls: contiguous 1KB bursts per store.
//   All output stores are nontemporal: the 682 MB write stream bypasses
//   L2/L3 retention so the 169 MB input stays Infinity-Cache-resident
//   across graph replays (read becomes L3-hit instead of HBM fetch).
// d_out (f32): b_pred_loc [N,5,4] | b_cls [N,5,80] | b_conf [N,5], N=B*784.

#define CPW 16      // cells per wave
#define ROW 105     // floats per cell

typedef float vf4 __attribute__((ext_vector_type(4)));  // nt-store-compatible

__device__ __forceinline__ float fsig(float x) {
    return __builtin_amdgcn_rcpf(1.0f + __expf(-x));
}

__device__ __forceinline__ void nt_store4(float* p, float a, float b, float c, float d) {
    vf4 v = {a, b, c, d};
    __builtin_nontemporal_store(v, reinterpret_cast<vf4*>(p));
}

__global__ __launch_bounds__(256) void det_fused(
    const float* __restrict__ in, float* __restrict__ out,
    int total_cells, size_t cls_off, size_t conf_off)
{
    __shared__ float s_row[4][CPW * ROW];   // 26880 B
    __shared__ float s_scale[4][CPW * 5];   // conf * inv_sum

    const int w    = threadIdx.x >> 6;
    const int lane = threadIdx.x & 63;
    const int cell0 = (blockIdx.x * 4 + w) * CPW;   // this wave's first cell
    if (cell0 >= total_cells) return;
    const int ncell = min(CPW, total_cells - cell0);

    float* __restrict__ row = s_row[w];
    float* __restrict__ scl = s_scale[w];

    // ---- A: wave-private coalesced load into LDS ----
    {
        const float* __restrict__ src = in + (size_t)cell0 * ROW;
        const int nflt = ncell * ROW;
        const int nv = nflt >> 2;
        const float4* __restrict__ s4 = reinterpret_cast<const float4*>(src);
        float4* d4 = reinterpret_cast<float4*>(row);
        for (int i = lane; i < nv; i += 64) d4[i] = s4[i];
        for (int i = (nv << 2) + lane; i < nflt; i += 64) row[i] = src[i];
    }
    __builtin_amdgcn_wave_barrier();

    // ---- B1: softmax inv-denominator, kept in registers via 2 shuffles ----
    float inv_c;                                   // valid for c = lane&15
    {
        const int c = lane & 15;                   // cell within wave
        const int part = lane >> 4;                // 0..3, 20 logits each
        float s = 0.0f;
        const float* __restrict__ r = row + c * ROW + 25 + part * 20;
        #pragma unroll
        for (int j = 0; j < 20; ++j) s += __expf(r[j]);
        s += __shfl_xor(s, 16);
        s += __shfl_xor(s, 32);
        inv_c = __builtin_amdgcn_rcpf(s);          // every lane: sum for its c
    }
    __builtin_amdgcn_wave_barrier();

    // ---- B2: sigmoids, boxes, conf, scales ----
    for (int p = lane; p < ncell * 5; p += 64) {
        const int c = p / 5;
        const int a = p - c * 5;
        const float inv = __shfl(inv_c, c);        // c < 16
        const float* __restrict__ lc = row + c * ROW + a * 5;
        const float sx = fsig(lc[0]);
        const float sy = fsig(lc[1]);
        const float sw = fsig(lc[2]);
        const float sh = fsig(lc[3]);
        const float cf = fsig(lc[4]);
        scl[p] = cf * inv;

        const int gcell = cell0 + c;
        __builtin_nontemporal_store(cf, out + conf_off + (size_t)gcell * 5 + a);

        const int cell28 = gcell % 784;            // gy*28 + gx
        const float gx = (float)(cell28 % 28);
        const float gy = (float)(cell28 / 28);
        const float invS = 1.0f / 28.0f;
        const float px = (sx + gx) * invS;
        const float py = (sy + gy) * invS;
        const float hw = sw * 0.5f;
        const float hh = sh * 0.5f;
        nt_store4(out + ((size_t)gcell * 5 + a) * 4,
                  px - hw, py - hh, px + hw, py + hh);
    }
    __builtin_amdgcn_wave_barrier();

    // ---- C: b_cls, lane <-> linear float4 => contiguous 1KB store bursts ----
    {
        float* __restrict__ cls = out + cls_off + (size_t)cell0 * 400;
        const int nvec = ncell * 100;              // float4 count for this wave
        for (int v = lane; v < nvec; v += 64) {
            const int c  = v / 100;                // cell in wave
            const int r  = v - c * 100;
            const int a  = r / 20;                 // anchor
            const int c4 = r - a * 20;             // class group
            const float* __restrict__ lp = row + c * ROW + 25 + c4 * 4;
            const float s = scl[c * 5 + a];
            nt_store4(cls + (size_t)v * 4,
                      __expf(lp[0]) * s, __expf(lp[1]) * s,
                      __expf(lp[2]) * s, __expf(lp[3]) * s);
        }
    }
}

extern "C" void kernel_launch(void* const* d_in, const int* in_sizes, int n_in,
                              void* d_out, int out_size, void* d_ws, size_t ws_size,
                              hipStream_t stream) {
    const float* in = (const float*)d_in[0];
    float* out = (float*)d_out;

    const size_t total_cells = (size_t)in_sizes[0] / 105;   // B * 784
    const size_t anchors     = total_cells * 5;
    const size_t cls_off     = anchors * 4;                 // after b_pred_loc
    const size_t conf_off    = cls_off + anchors * 80;      // after b_cls

    const int cells_per_block = 4 * CPW;                    // 64
    const int blocks = (int)((total_cells + cells_per_block - 1) / cells_per_block);
    det_fused<<<blocks, 256, 0, stream>>>(in, out, (int)total_cells,
                                          cls_off, conf_off);
}